// Round 4
// baseline (91.247 us; speedup 1.0000x reference)
//
#include <hip/hip_runtime.h>
#include <math.h>

// ---------------- common ----------------
#define NCc     16          // cells per dim
#define NCELLS  4096        // 16^3
#define CELLW   16.0f
#define QCUT    40.0f       // quad cutoff: dropped contribution <= 0.1*e^-20 each

typedef float v2f __attribute__((ext_vector_type(2)));
static __device__ __forceinline__ v2f s2(float s) { v2f r; r.x = s; r.y = s; return r; }
static __device__ __forceinline__ v2f pkfma(v2f a, v2f b, v2f c) {
    return __builtin_elementwise_fma(a, b, c);
}
static __device__ __forceinline__ float fexp2(float x) {
#if __has_builtin(__builtin_amdgcn_exp2f)
    return __builtin_amdgcn_exp2f(x);
#else
    return exp2f(x);
#endif
}

static __device__ __forceinline__ int cell_of(float x, float y, float z) {
    int cx = min(NCc - 1, max(0, (int)(x * (1.0f / CELLW))));
    int cy = min(NCc - 1, max(0, (int)(y * (1.0f / CELLW))));
    int cz = min(NCc - 1, max(0, (int)(z * (1.0f / CELLW))));
    return (cz << 8) | (cy << 4) | cx;
}

// squared distance from Gaussian center to cell AABB (edge cells open-ended)
static __device__ __forceinline__ float cell_d2(int c, float mx, float my, float mz) {
    int cx = c & 15, cy = (c >> 4) & 15, cz = c >> 8;
    float lx = cx * CELLW, hx = lx + CELLW;
    float ly = cy * CELLW, hy = ly + CELLW;
    float lz = cz * CELLW, hz = lz + CELLW;
    if (cx == 0) lx = -1e30f;  if (cx == NCc - 1) hx = 1e30f;
    if (cy == 0) ly = -1e30f;  if (cy == NCc - 1) hy = 1e30f;
    if (cz == 0) lz = -1e30f;  if (cz == NCc - 1) hz = 1e30f;
    float dx = fmaxf(fmaxf(lx - mx, mx - hx), 0.0f);
    float dy = fmaxf(fmaxf(ly - my, my - hy), 0.0f);
    float dz = fmaxf(fmaxf(lz - mz, mz - hz), 0.0f);
    return dx * dx + dy * dy + dz * dz;
}

// ---------------- L1: per-Gaussian precompute (+aux) and point histogram ----------------
__global__ __launch_bounds__(256) void k_pre_hist(
    const float* __restrict__ positions,
    const float* __restrict__ log_scales,
    const float* __restrict__ rotations,
    const float* __restrict__ weights,
    const float* __restrict__ points,
    float* __restrict__ params,     // N x 12
    float* __restrict__ aux,        // N x 4: ux,uy,uz,r2
    unsigned* __restrict__ pcnt,    // NCELLS
    int N, int M, int nPre)
{
    if ((int)blockIdx.x < nPre) {
        int i = blockIdx.x * 256 + threadIdx.x;
        if (i >= N) return;

        float s0 = expf(log_scales[3*i+0]);
        float s1 = expf(log_scales[3*i+1]);
        float s2_ = expf(log_scales[3*i+2]);
        float v0 = s0*s0, v1 = s1*s1, v2 = s2_*s2_;

        float qw = rotations[4*i+0], qx = rotations[4*i+1];
        float qy = rotations[4*i+2], qz = rotations[4*i+3];
        float nrm = sqrtf(qw*qw + qx*qx + qy*qy + qz*qz) + 1e-8f;
        float inv = 1.0f / nrm;
        qw *= inv; qx *= inv; qy *= inv; qz *= inv;

        float r00 = 1.f - 2.f*(qy*qy + qz*qz);
        float r01 = 2.f*(qx*qy - qz*qw);
        float r02 = 2.f*(qx*qz + qy*qw);
        float r10 = 2.f*(qx*qy + qz*qw);
        float r11 = 1.f - 2.f*(qx*qx + qz*qz);
        float r12 = 2.f*(qy*qz - qx*qw);
        float r20 = 2.f*(qx*qz - qy*qw);
        float r21 = 2.f*(qy*qz + qx*qw);
        float r22 = 1.f - 2.f*(qx*qx + qy*qy);

        float a = r00*r00*v0 + r01*r01*v1 + r02*r02*v2 + 1e-6f;
        float b = r00*r10*v0 + r01*r11*v1 + r02*r12*v2;
        float c = r00*r20*v0 + r01*r21*v1 + r02*r22*v2;
        float d = r10*r10*v0 + r11*r11*v1 + r12*r12*v2 + 1e-6f;
        float e = r10*r20*v0 + r11*r21*v1 + r12*r22*v2;
        float f = r20*r20*v0 + r21*r21*v1 + r22*r22*v2 + 1e-6f;

        float m00 = d*f - e*e;
        float m01 = c*e - b*f;
        float m02 = b*e - c*d;
        float det = a*m00 + b*m01 + c*m02;
        float id  = 1.0f / det;
        float A00 = m00*id, A01 = m01*id, A02 = m02*id;
        float A11 = (a*f - c*c)*id;
        float A12 = (c*b - a*e)*id;
        float A22 = (a*d - b*b)*id;

        float ux = positions[3*i+0], uy = positions[3*i+1], uz = positions[3*i+2];
        float bx = A00*ux + A01*uy + A02*uz;
        float by = A01*ux + A11*uy + A12*uz;
        float bz = A02*ux + A12*uy + A22*uz;
        float cq = ux*bx + uy*by + uz*bz;

        const float kk = -0.72134752044448170368f; // -0.5 * log2(e)
        float* P = params + 12*i;
        P[0]  = kk*A00;      P[1]  = kk*A11;      P[2]  = kk*A22;      P[3] = 2.f*kk*A01;
        P[4]  = 2.f*kk*A02;  P[5]  = 2.f*kk*A12;  P[6]  = -2.f*kk*bx;  P[7] = -2.f*kk*by;
        P[8]  = -2.f*kk*bz;  P[9]  = kk*cq;       P[10] = weights[i];  P[11] = 0.f;

        // Gershgorin bound on lambda_max(cov) -> cull radius^2
        float L = fmaxf(fmaxf(a + fabsf(b) + fabsf(c),
                              fabsf(b) + d + fabsf(e)),
                        fabsf(c) + fabsf(e) + f);
        aux[4*i+0] = ux; aux[4*i+1] = uy; aux[4*i+2] = uz; aux[4*i+3] = QCUT * L;
    } else {
        int m = ((int)blockIdx.x - nPre) * 256 + threadIdx.x;
        if (m >= M) return;
        int c = cell_of(points[3*m+0], points[3*m+1], points[3*m+2]);
        atomicAdd(&pcnt[c], 1u);
    }
}

// ---------------- exclusive scan of 4096 u32 by one 256-thread block ----------------
static __device__ void scan4096(const unsigned* __restrict__ cnt, unsigned* __restrict__ start)
{
    __shared__ unsigned sh[256];
    int tid = threadIdx.x;
    int base = tid * 16;
    unsigned v[16];
#pragma unroll
    for (int i = 0; i < 16; ++i) v[i] = cnt[base + i];
    unsigned run = 0;
#pragma unroll
    for (int i = 0; i < 16; ++i) { unsigned t = v[i]; v[i] = run; run += t; }
    sh[tid] = run;
    __syncthreads();
    for (int d = 1; d < 256; d <<= 1) {
        unsigned add = (tid >= d) ? sh[tid - d] : 0u;
        __syncthreads();
        sh[tid] += add;
        __syncthreads();
    }
    unsigned ex = sh[tid] - run;
#pragma unroll
    for (int i = 0; i < 16; ++i) start[base + i] = ex + v[i];
}

// ---------------- L2: block0 scans pcnt->pstart; blocks 1..NCELLS count list lens ----------------
__global__ __launch_bounds__(256) void k_scan_count(
    const unsigned* __restrict__ pcnt, unsigned* __restrict__ pstart,
    const float4* __restrict__ aux4, unsigned* __restrict__ lcnt, int N)
{
    if (blockIdx.x == 0) { scan4096(pcnt, pstart); return; }
    int c = blockIdx.x - 1;
    __shared__ unsigned s;
    if (threadIdx.x == 0) s = 0;
    __syncthreads();
    unsigned local = 0;
    for (int g = threadIdx.x; g < N; g += 256) {
        float4 a = aux4[g];
        if (cell_d2(c, a.x, a.y, a.z) <= a.w) local++;
    }
    atomicAdd(&s, local);
    __syncthreads();
    if (threadIdx.x == 0) lcnt[c] = s;
}

// ---------------- L3: block0 scans lcnt->lstart; blocks 1.. scatter points ----------------
__global__ __launch_bounds__(256) void k_scan_scatter(
    const unsigned* __restrict__ lcnt, unsigned* __restrict__ lstart,
    const float* __restrict__ points, const unsigned* __restrict__ pstart,
    unsigned* __restrict__ pfill, unsigned* __restrict__ sorted, int M)
{
    if (blockIdx.x == 0) { scan4096(lcnt, lstart); return; }
    int m = ((int)blockIdx.x - 1) * 256 + threadIdx.x;
    if (m >= M) return;
    int c = cell_of(points[3*m+0], points[3*m+1], points[3*m+2]);
    unsigned r = atomicAdd(&pfill[c], 1u);
    sorted[pstart[c] + r] = (unsigned)m;
}

// ---------------- L4: deterministic ordered list fill (1 wave per cell) ----------------
__global__ __launch_bounds__(64) void k_fill(
    const float4* __restrict__ aux4, const unsigned* __restrict__ lstart,
    unsigned* __restrict__ lists, int N, unsigned cap)
{
    int c = blockIdx.x;
    int lane = threadIdx.x;
    unsigned pos = lstart[c];
    unsigned long long ltmask = (lane == 63) ? 0x7fffffffffffffffULL : ((1ULL << lane) - 1ULL);
    for (int g0 = 0; g0 < N; g0 += 64) {
        int g = g0 + lane;
        bool keep = false;
        if (g < N) {
            float4 a = aux4[g];
            keep = cell_d2(c, a.x, a.y, a.z) <= a.w;
        }
        unsigned long long mask = __ballot(keep);
        if (keep) {
            unsigned idx = pos + (unsigned)__popcll(mask & ltmask);
            if (idx < cap) lists[idx] = (unsigned)g;
        }
        pos += (unsigned)__popcll(mask);
    }
}

// ---------------- L5: eval — one cell per 128-thread block, 16 pts x 8 strips ----------------
__global__ __launch_bounds__(128) void k_eval(
    const float* __restrict__ points, const float4* __restrict__ P4,
    const unsigned* __restrict__ pcnt, const unsigned* __restrict__ pstart,
    const unsigned* __restrict__ sorted,
    const unsigned* __restrict__ lcnt, const unsigned* __restrict__ lstart,
    const unsigned* __restrict__ lists,
    float* __restrict__ out)
{
    int c = blockIdx.x;
    int tid = threadIdx.x;
    int pl = tid & 15;          // point slot 0..15
    int strip = tid >> 4;       // 0..7
    int npts = (int)pcnt[c];
    unsigned ps = pstart[c];
    int nls = (int)lcnt[c];
    unsigned ls = lstart[c];

    for (int pb = 0; pb < npts; pb += 16) {
        int pi = pb + pl;
        bool act = pi < npts;
        unsigned m = sorted[ps + (act ? pi : 0)];
        float x = points[3*m+0], y = points[3*m+1], z = points[3*m+2];
        float xx = x*x, yy = y*y, zz = z*z;
        float xy = x*y, xz = x*z, yz = y*z;

        float acc = 0.f;
        int j = strip;
        int gn = (j < nls) ? (int)lists[ls + j] : 0;
        for (; j < nls; j += 8) {
            int g = gn;
            int jn = j + 8;
            if (jn < nls) gn = (int)lists[ls + jn];
            float4 q0 = P4[3*g + 0];   // Q00,Q11,Q22,Q01
            float4 q1 = P4[3*g + 1];   // Q02,Q12,Lx,Ly
            float4 q2 = P4[3*g + 2];   // Lz,C,W,pad

            float t0 = fmaf(q0.x, xx, q2.y);
            t0 = fmaf(q0.w, xy, t0);
            t0 = fmaf(q1.z, x,  t0);
            float t1 = q0.y * yy;
            t1 = fmaf(q1.y, yz, t1);
            t1 = fmaf(q1.w, y,  t1);
            float t2 = q0.z * zz;
            t2 = fmaf(q1.x, xz, t2);
            t2 = fmaf(q2.x, z,  t2);
            float e2 = (t0 + t1) + t2;
            acc = fmaf(q2.z, fexp2(e2), acc);
        }
        // reduce the 4 strips within this wave (lanes share pl mod 16)
        acc += __shfl_xor(acc, 16);
        acc += __shfl_xor(acc, 32);
        if (act && (tid & 63) < 16) atomicAdd(&out[m], acc);
    }
}

// ---------------- dense fallback (R3 kernel) ----------------
#define NSPLIT 32
#define COARSEN 4
__global__ __launch_bounds__(256, 8) void gbf_eval_dense(
    const float* __restrict__ points,
    const float4* __restrict__ params,
    float* __restrict__ out, int M, int N, int nPer)
{
    int p0 = blockIdx.x * (256 * COARSEN) + threadIdx.x;
    int p1 = p0 + 256, p2 = p0 + 512, p3 = p0 + 768;
    int c0 = min(p0, M-1), c1 = min(p1, M-1), c2 = min(p2, M-1), c3 = min(p3, M-1);

    v2f X1, Y1, Z1, X2_, Y2_, Z2_;
    X1.x = points[3*c0+0]; X1.y = points[3*c1+0];
    Y1.x = points[3*c0+1]; Y1.y = points[3*c1+1];
    Z1.x = points[3*c0+2]; Z1.y = points[3*c1+2];
    X2_.x = points[3*c2+0]; X2_.y = points[3*c3+0];
    Y2_.x = points[3*c2+1]; Y2_.y = points[3*c3+1];
    Z2_.x = points[3*c2+2]; Z2_.y = points[3*c3+2];

    v2f XX1 = X1*X1, YY1 = Y1*Y1, ZZ1 = Z1*Z1;
    v2f XY1 = X1*Y1, XZ1 = X1*Z1, YZ1 = Y1*Z1;
    v2f XX2 = X2_*X2_, YY2 = Y2_*Y2_, ZZ2 = Z2_*Z2_;
    v2f XY2 = X2_*Y2_, XZ2 = X2_*Z2_, YZ2 = Y2_*Z2_;

    int jbase = blockIdx.y * nPer;
    int jend = min(nPer, N - jbase);
    int base = jbase * 3;
    v2f acc1; acc1.x = 0.f; acc1.y = 0.f;
    v2f acc2 = acc1;

#pragma unroll 2
    for (int j = 0; j < jend; ++j) {
        float4 q0 = params[base + 3*j + 0];
        float4 q1 = params[base + 3*j + 1];
        float4 q2 = params[base + 3*j + 2];

        v2f t0 = pkfma(s2(q0.x), XX1, s2(q2.y));
        t0 = pkfma(s2(q0.w), XY1, t0);
        t0 = pkfma(s2(q1.z), X1,  t0);
        v2f t1 = s2(q0.y) * YY1;
        t1 = pkfma(s2(q1.y), YZ1, t1);
        t1 = pkfma(s2(q1.w), Y1,  t1);
        v2f t2 = s2(q0.z) * ZZ1;
        t2 = pkfma(s2(q1.x), XZ1, t2);
        t2 = pkfma(s2(q2.x), Z1,  t2);
        v2f e1 = (t0 + t1) + t2;

        v2f u0 = pkfma(s2(q0.x), XX2, s2(q2.y));
        u0 = pkfma(s2(q0.w), XY2, u0);
        u0 = pkfma(s2(q1.z), X2_, u0);
        v2f u1 = s2(q0.y) * YY2;
        u1 = pkfma(s2(q1.y), YZ2, u1);
        u1 = pkfma(s2(q1.w), Y2_, u1);
        v2f u2 = s2(q0.z) * ZZ2;
        u2 = pkfma(s2(q1.x), XZ2, u2);
        u2 = pkfma(s2(q2.x), Z2_, u2);
        v2f e2 = (u0 + u1) + u2;

        v2f g1, g2;
        g1.x = fexp2(e1.x); g1.y = fexp2(e1.y);
        g2.x = fexp2(e2.x); g2.y = fexp2(e2.y);
        acc1 = pkfma(s2(q2.z), g1, acc1);
        acc2 = pkfma(s2(q2.z), g2, acc2);
    }
    if (p0 < M) atomicAdd(&out[p0], acc1.x);
    if (p1 < M) atomicAdd(&out[p1], acc1.y);
    if (p2 < M) atomicAdd(&out[p2], acc2.x);
    if (p3 < M) atomicAdd(&out[p3], acc2.y);
}

// ---------------- host ----------------
extern "C" void kernel_launch(void* const* d_in, const int* in_sizes, int n_in,
                              void* d_out, int out_size, void* d_ws, size_t ws_size,
                              hipStream_t stream)
{
    const float* points     = (const float*)d_in[0];
    const float* positions  = (const float*)d_in[1];
    const float* log_scales = (const float*)d_in[2];
    const float* rotations  = (const float*)d_in[3];
    const float* weights    = (const float*)d_in[4];
    int M = in_sizes[0] / 3;
    int N = in_sizes[4];
    float* out = (float*)d_out;

    // workspace layout
    char* w = (char*)d_ws;
    size_t o = 0;
    float*    params = (float*)(w + o);    o += (size_t)N * 12 * 4;
    float*    aux    = (float*)(w + o);    o += (size_t)N * 4 * 4;
    unsigned* pcnt   = (unsigned*)(w + o); o += NCELLS * 4;
    unsigned* pfill  = (unsigned*)(w + o); o += NCELLS * 4;
    unsigned* lcnt   = (unsigned*)(w + o); o += NCELLS * 4;
    unsigned* pstart = (unsigned*)(w + o); o += NCELLS * 4;
    unsigned* lstart = (unsigned*)(w + o); o += NCELLS * 4;
    unsigned* sorted = (unsigned*)(w + o); o += (size_t)M * 4;
    unsigned* lists  = (unsigned*)(w + o);
    size_t capB = (ws_size > o) ? (ws_size - o) : 0;
    unsigned cap = (unsigned)(capB / 4);

    int nPre  = (N + 255) / 256;
    int nHist = (M + 255) / 256;

    if (capB < (8u << 20)) {
        // dense fallback
        hipMemsetAsync(d_out, 0, (size_t)out_size * sizeof(float), stream);
        k_pre_hist<<<dim3(nPre), dim3(256), 0, stream>>>(
            positions, log_scales, rotations, weights, points,
            params, aux, pcnt, N, M, nPre);   // only precompute blocks launched
        int nPer = (N + NSPLIT - 1) / NSPLIT;
        dim3 grid((M + 256 * COARSEN - 1) / (256 * COARSEN), NSPLIT);
        gbf_eval_dense<<<grid, dim3(256), 0, stream>>>(points, (const float4*)params, out, M, N, nPer);
        return;
    }

    hipMemsetAsync(pcnt, 0, NCELLS * 3 * 4, stream);              // pcnt, pfill, lcnt
    hipMemsetAsync(d_out, 0, (size_t)out_size * sizeof(float), stream);

    k_pre_hist<<<dim3(nPre + nHist), dim3(256), 0, stream>>>(
        positions, log_scales, rotations, weights, points,
        params, aux, pcnt, N, M, nPre);

    k_scan_count<<<dim3(1 + NCELLS), dim3(256), 0, stream>>>(
        pcnt, pstart, (const float4*)aux, lcnt, N);

    k_scan_scatter<<<dim3(1 + nHist), dim3(256), 0, stream>>>(
        lcnt, lstart, points, pstart, pfill, sorted, M);

    k_fill<<<dim3(NCELLS), dim3(64), 0, stream>>>(
        (const float4*)aux, lstart, lists, N, cap);

    k_eval<<<dim3(NCELLS), dim3(128), 0, stream>>>(
        points, (const float4*)params, pcnt, pstart, sorted, lcnt, lstart, lists, out);
}